// Round 4
// baseline (2231.533 us; speedup 1.0000x reference)
//
#include <hip/hip_runtime.h>
#include <hip/hip_cooperative_groups.h>

typedef unsigned long long u64;
#define V0TOK 32000
#define EDIM  1024

__device__ __forceinline__ float dot4(float4 a, float4 b) {
    return fmaf(a.x, b.x, fmaf(a.y, b.y, fmaf(a.z, b.z, a.w * b.w)));
}

// ---------------------------------------------------------------------------
// Cooperative RNN kernel: 256 blocks x 256 threads (1 block/CU).
// Block b owns h-indices j = 4b+w (wave w): GRU rows {j, 1024+j, 2048+j}.
// W_hh rows in VGPRs; W_ih x-half in LDS; W_ih c-half folded into gic once.
// h exchange: plain relaxed agent stores into parity double-buffer hbuf +
// one RELEASE fetch_add per value on 32 counters. Consumers poll ONLY the
// 32 counters (wave0, lanes 0-31, ACQUIRE, s_sleep-paced) -> ~32x less spin
// traffic than tag polling; then fetch data once and share via LDS.
// ABA-safe: producer overwrites parity p only after acquiring counters that
// release-follow every block's reads of p.
// ---------------------------------------------------------------------------
__global__ __launch_bounds__(256, 1) void k_rnn(
    const int* __restrict__ diag, const int* __restrict__ proc,
    const int* __restrict__ med,  const int* __restrict__ dtok,
    const float* __restrict__ enc, const float* __restrict__ dec,
    const float* __restrict__ attw,
    const float* __restrict__ wih, const float* __restrict__ whh,
    const float* __restrict__ bih, const float* __restrict__ bhh,
    float* __restrict__ ctx_ws, float* __restrict__ c_ws,
    unsigned* __restrict__ cnt, float* __restrict__ hbuf,
    float* __restrict__ hrelu)
{
    const int b = blockIdx.x, tid = threadIdx.x;
    const int w = tid >> 6, l = tid & 63;

    __shared__ float Wx[12 * 1024];     // 48KB: W_ih x-half rows, row (g*4+w)
    __shared__ float sm[320];
    __shared__ float red1[4], red2[4];
    __shared__ float hlds[1024];

    // ---- Phase A: clear counters (replay determinism) + ctx scores ----
    if (b == 0 && tid < 32)
        __hip_atomic_store(&cnt[tid], 0u, __ATOMIC_RELAXED, __HIP_MEMORY_SCOPE_AGENT);
    if (b < 80) {
        int i = 4*b + w;   // 0..319
        int ridx = (i < 128) ? diag[i] : (i < 192 ? proc[i-128] : med[i-192]);
        const float4* row = (const float4*)(enc + (size_t)ridx * EDIM);
        const float4* we  = (const float4*)(attw + EDIM);   // w_e = attn_w[0, E:]
        float p = 0.f;
        #pragma unroll
        for (int m = 0; m < 4; m++) p += dot4(row[l + 64*m], we[l + 64*m]);
        #pragma unroll
        for (int off = 32; off; off >>= 1) p += __shfl_xor(p, off);
        if (l == 0) ctx_ws[i] = p;
    }
    __threadfence();
    cooperative_groups::this_grid().sync();
    __threadfence();

    // ---- Phase B: per-block softmax (redundant) + c slice ----
    {
        float s1 = ctx_ws[tid];
        float s2 = (tid < 64) ? ctx_ws[256 + tid] : -1e30f;
        float mx = fmaxf(s1, s2);
        #pragma unroll
        for (int off = 32; off; off >>= 1) mx = fmaxf(mx, __shfl_xor(mx, off));
        if (l == 0) red1[w] = mx;
        __syncthreads();
        mx = fmaxf(fmaxf(red1[0], red1[1]), fmaxf(red1[2], red1[3]));
        float e1 = expf(s1 - mx);
        float e2 = (tid < 64) ? expf(s2 - mx) : 0.f;
        float ss = e1 + e2;
        #pragma unroll
        for (int off = 32; off; off >>= 1) ss += __shfl_xor(ss, off);
        if (l == 0) red2[w] = ss;
        __syncthreads();
        float tot = red2[0] + red2[1] + red2[2] + red2[3];
        sm[tid] = e1 / tot;
        if (tid < 64) sm[256 + tid] = e2 / tot;
        __syncthreads();

        int e = 4*b + w;
        float p = 0.f;
        for (int i = l; i < 320; i += 64) {
            int ridx = (i < 128) ? diag[i] : (i < 192 ? proc[i-128] : med[i-192]);
            p += sm[i] * enc[(size_t)ridx * EDIM + e];
        }
        #pragma unroll
        for (int off = 32; off; off >>= 1) p += __shfl_xor(p, off);
        if (l == 0) c_ws[e] = p;
    }
    __threadfence();
    cooperative_groups::this_grid().sync();
    __threadfence();

    // ---- Phase C ----
    const int jr = 4*b + w, jz = 1024 + jr, jn = 2048 + jr;

    // Stage W_ih x-half rows into LDS
    {
        const float4* s_r = (const float4*)(wih + (size_t)jr * 2048 + 1024);
        const float4* s_z = (const float4*)(wih + (size_t)jz * 2048 + 1024);
        const float4* s_n = (const float4*)(wih + (size_t)jn * 2048 + 1024);
        float4* d_r = (float4*)(Wx + (0*4 + w) * 1024);
        float4* d_z = (float4*)(Wx + (1*4 + w) * 1024);
        float4* d_n = (float4*)(Wx + (2*4 + w) * 1024);
        #pragma unroll
        for (int m = 0; m < 4; m++) {
            d_r[l + 64*m] = s_r[l + 64*m];
            d_z[l + 64*m] = s_z[l + 64*m];
            d_n[l + 64*m] = s_n[l + 64*m];
        }
    }

    // W_hh rows -> VGPRs
    float4 whr[4], whz[4], whn[4];
    {
        const float4* qr = (const float4*)(whh + (size_t)jr * 1024);
        const float4* qz = (const float4*)(whh + (size_t)jz * 1024);
        const float4* qn = (const float4*)(whh + (size_t)jn * 1024);
        #pragma unroll
        for (int m = 0; m < 4; m++) { whr[m] = qr[l + 64*m]; whz[m] = qz[l + 64*m]; whn[m] = qn[l + 64*m]; }
    }

    float4 c4[4], h4[4];
    {
        const float4* cp = (const float4*)c_ws;
        const float4* hp = (const float4*)(dec + (size_t)V0TOK * EDIM);  // h0 = x_0
        #pragma unroll
        for (int m = 0; m < 4; m++) { c4[m] = cp[l + 64*m]; h4[m] = hp[l + 64*m]; }
    }
    const float b_r  = bih[jr] + bhh[jr];
    const float b_z  = bih[jz] + bhh[jz];
    const float b_ni = bih[jn];
    const float b_nh = bhh[jn];

    float gic_r = 0.f, gic_z = 0.f, gic_n = 0.f;
    {
        const float4* pr = (const float4*)(wih + (size_t)jr * 2048);
        const float4* pz = (const float4*)(wih + (size_t)jz * 2048);
        const float4* pn = (const float4*)(wih + (size_t)jn * 2048);
        #pragma unroll
        for (int m = 0; m < 4; m++) {
            gic_r += dot4(pr[l + 64*m], c4[m]);
            gic_z += dot4(pz[l + 64*m], c4[m]);
            gic_n += dot4(pn[l + 64*m], c4[m]);
        }
    }

    __syncthreads();   // Wx staged

    const float4* WxR = (const float4*)(Wx + (0*4 + w) * 1024);
    const float4* WxZ = (const float4*)(Wx + (1*4 + w) * 1024);
    const float4* WxN = (const float4*)(Wx + (2*4 + w) * 1024);

    int tokreg = dtok[l];

    // gx for t=0 (x_0 == h0)
    float gxr = gic_r, gxz = gic_z, gxn = gic_n;
    #pragma unroll
    for (int m = 0; m < 4; m++) {
        gxr += dot4(WxR[l + 64*m], h4[m]);
        gxz += dot4(WxZ[l + 64*m], h4[m]);
        gxn += dot4(WxN[l + 64*m], h4[m]);
    }
    float4 xv[4];
    {
        int tok1 = __shfl(tokreg, 0);
        const float4* xp = (const float4*)(dec + (size_t)tok1 * EDIM);
        #pragma unroll
        for (int m = 0; m < 4; m++) xv[m] = xp[l + 64*m];
    }

    for (int t = 0; t < 65; t++) {
        float hr = 0.f, hz = 0.f, hn_ = 0.f;
        #pragma unroll
        for (int m = 0; m < 4; m++) {
            hr  += dot4(whr[m], h4[m]);
            hz  += dot4(whz[m], h4[m]);
            hn_ += dot4(whn[m], h4[m]);
        }
        float sr = gxr + hr, sz = gxz + hz, sni = gxn, snh = hn_;
        #pragma unroll
        for (int off = 32; off; off >>= 1) {
            sr  += __shfl_xor(sr, off);  sz  += __shfl_xor(sz, off);
            sni += __shfl_xor(sni, off); snh += __shfl_xor(snh, off);
        }
        float rg = 1.f / (1.f + expf(-(sr + b_r)));
        float zg = 1.f / (1.f + expf(-(sz + b_z)));
        float ng = tanhf(sni + b_ni + rg * (snh + b_nh));

        int mi = b >> 6;
        float4 hs = (mi == 0) ? h4[0] : (mi == 1) ? h4[1] : (mi == 2) ? h4[2] : h4[3];
        float hv = (w == 0) ? hs.x : (w == 1) ? hs.y : (w == 2) ? hs.z : hs.w;
        hv = __shfl(hv, b & 63);
        float hnew = (1.f - zg) * ng + zg * hv;

        if (t < 64) {
            const int par = (t + 1) & 1;
            if (l == 0) {
                hrelu[t * 1024 + jr] = fmaxf(hnew, 0.f);
                // publish value, then release-add: same thread => release orders the store
                __hip_atomic_store(&hbuf[par * 1024 + jr], hnew,
                                   __ATOMIC_RELAXED, __HIP_MEMORY_SCOPE_AGENT);
                __hip_atomic_fetch_add(&cnt[jr & 31], 1u,
                                       __ATOMIC_RELEASE, __HIP_MEMORY_SCOPE_AGENT);
            }

            // ---- overlap window: gx(t+1) + x prefetch while adds propagate ----
            gxr = gic_r; gxz = gic_z; gxn = gic_n;
            #pragma unroll
            for (int m = 0; m < 4; m++) {
                gxr += dot4(WxR[l + 64*m], xv[m]);
                gxz += dot4(WxZ[l + 64*m], xv[m]);
                gxn += dot4(WxN[l + 64*m], xv[m]);
            }
            if (t < 63) {
                int tok = __shfl(tokreg, t + 1);
                const float4* xp = (const float4*)(dec + (size_t)tok * EDIM);
                #pragma unroll
                for (int m = 0; m < 4; m++) xv[m] = xp[l + 64*m];
            }

            // ---- poll 32 counters only (wave 0, lanes 0-31) ----
            if (w == 0 && l < 32) {
                const unsigned target = 32u * (unsigned)(t + 1);
                while (__hip_atomic_load(&cnt[l], __ATOMIC_ACQUIRE,
                                         __HIP_MEMORY_SCOPE_AGENT) < target)
                    __builtin_amdgcn_s_sleep(1);
            }
            __syncthreads();

            // ---- fetch h(t+1): 4 floats/thread, share via LDS ----
            float4 mine;
            mine.x = __hip_atomic_load(&hbuf[par*1024 + 4*tid + 0], __ATOMIC_RELAXED, __HIP_MEMORY_SCOPE_AGENT);
            mine.y = __hip_atomic_load(&hbuf[par*1024 + 4*tid + 1], __ATOMIC_RELAXED, __HIP_MEMORY_SCOPE_AGENT);
            mine.z = __hip_atomic_load(&hbuf[par*1024 + 4*tid + 2], __ATOMIC_RELAXED, __HIP_MEMORY_SCOPE_AGENT);
            mine.w = __hip_atomic_load(&hbuf[par*1024 + 4*tid + 3], __ATOMIC_RELAXED, __HIP_MEMORY_SCOPE_AGENT);
            ((float4*)hlds)[tid] = mine;
            __syncthreads();
            #pragma unroll
            for (int m = 0; m < 4; m++) h4[m] = ((const float4*)hlds)[l + 64*m];
        } else {
            if (l == 0) hrelu[64 * 1024 + jr] = fmaxf(hnew, 0.f);
        }
    }
}

// ---------------------------------------------------------------------------
// logits = out_w @ relu(H)^T + out_b, owner-computes:
// block = 16 v-rows; thread (vl=tid>>4, q=tid&15) owns W[v][4q..4q+4) of each
// 64-k chunk (coalesced 256B per 16 lanes), acc[65] in VGPRs (t-loop fully
// unrolled -> static indices), H chunk staged in LDS, 16-lane shfl reduce.
// ---------------------------------------------------------------------------
__global__ __launch_bounds__(256) void k_logits(
    const float* __restrict__ wo, const float* __restrict__ bo,
    const float* __restrict__ hrelu, float* __restrict__ out)
{
    __shared__ float Hs[65 * 68];
    const int tid = threadIdx.x;
    const int vl = tid >> 4, q = tid & 15;
    const int v  = blockIdx.x * 16 + vl;
    const int vc = (v < 32002) ? v : 0;
    const float* wrow = wo + (size_t)vc * 1024;
    const float bv = bo[vc];

    float acc[65];
    #pragma unroll
    for (int t = 0; t < 65; t++) acc[t] = 0.f;

    for (int kc = 0; kc < 16; kc++) {
        __syncthreads();
        for (int idx = tid; idx < 65 * 16; idx += 256) {
            int t = idx >> 4, m = idx & 15;
            *(float4*)(Hs + t * 68 + 4 * m) =
                *(const float4*)(hrelu + t * 1024 + kc * 64 + 4 * m);
        }
        float4 Wf = *(const float4*)(wrow + kc * 64 + 4 * q);
        __syncthreads();

        const float* hp = Hs + 4 * q;
        #pragma unroll
        for (int t = 0; t < 65; t++) {
            float4 h4 = *(const float4*)(hp + t * 68);
            acc[t] = fmaf(Wf.x, h4.x, acc[t]);
            acc[t] = fmaf(Wf.y, h4.y, acc[t]);
            acc[t] = fmaf(Wf.z, h4.z, acc[t]);
            acc[t] = fmaf(Wf.w, h4.w, acc[t]);
        }
    }

    // reduce over q (16-lane groups) and store
    #pragma unroll
    for (int t = 0; t < 65; t++) {
        float s = acc[t];
        s += __shfl_xor(s, 1);
        s += __shfl_xor(s, 2);
        s += __shfl_xor(s, 4);
        s += __shfl_xor(s, 8);
        if (q == 0 && v < 32002) out[(size_t)t * 32002 + v] = s + bv;
    }
}

// ---------------------------------------------------------------------------
extern "C" void kernel_launch(void* const* d_in, const int* in_sizes, int n_in,
                              void* d_out, int out_size, void* d_ws, size_t ws_size,
                              hipStream_t stream) {
    const int*   diag = (const int*)d_in[0];
    const int*   proc = (const int*)d_in[1];
    const int*   med  = (const int*)d_in[2];
    const int*   dtok = (const int*)d_in[3];
    const float* enc  = (const float*)d_in[4];
    const float* dec  = (const float*)d_in[5];
    const float* attw = (const float*)d_in[6];
    // d_in[7] = attn_b: uniform shift, cancels in softmax -> unused
    const float* wih  = (const float*)d_in[8];
    const float* whh  = (const float*)d_in[9];
    const float* bih  = (const float*)d_in[10];
    const float* bhh  = (const float*)d_in[11];
    const float* wo   = (const float*)d_in[12];
    const float* bo   = (const float*)d_in[13];
    float* out = (float*)d_out;

    // ws: [0,1280) ctx | [2048,6144) c | [8192,+128) cnt | [12288,+8192) hbuf | [32768,+266240) hrelu
    float*    ctx_ws = (float*)d_ws;
    float*    c_ws   = (float*)((char*)d_ws + 2048);
    unsigned* cnt    = (unsigned*)((char*)d_ws + 8192);
    float*    hbuf   = (float*)((char*)d_ws + 12288);
    float*    hrelu  = (float*)((char*)d_ws + 32768);

    void* args[] = { (void*)&diag, (void*)&proc, (void*)&med, (void*)&dtok,
                     (void*)&enc, (void*)&dec, (void*)&attw,
                     (void*)&wih, (void*)&whh, (void*)&bih, (void*)&bhh,
                     (void*)&ctx_ws, (void*)&c_ws, (void*)&cnt, (void*)&hbuf,
                     (void*)&hrelu };
    hipLaunchCooperativeKernel((void*)k_rnn, dim3(256), dim3(256), args, 0, stream);

    k_logits<<<dim3(2001), dim3(256), 0, stream>>>(wo, bo, hrelu, out);
}

// Round 5
// 512.675 us; speedup vs baseline: 4.3527x; 4.3527x over previous
//
#include <hip/hip_runtime.h>
#include <hip/hip_cooperative_groups.h>

typedef unsigned long long u64;
#define V0TOK 32000
#define EDIM  1024

__device__ __forceinline__ float dot4(float4 a, float4 b) {
    return fmaf(a.x, b.x, fmaf(a.y, b.y, fmaf(a.z, b.z, a.w * b.w)));
}

// ---------------------------------------------------------------------------
// Cooperative RNN: 128 blocks x 512 threads (8 waves). Block b owns h rows
// j = 8b+w (wave w): GRU rows {j, 1024+j, 2048+j}. W_hh in VGPRs (48/lane),
// W_ih x-half in LDS (96KB), c-half folded into gic once.
// h exchange protocol (NO acquire/release anywhere in the hot loop -- R4
// showed agent RELEASE = dirty-L2 writeback storm, ACQUIRE = invalidate
// storm; 272MB/dispatch HBM writes):
//   producers: relaxed agent atomic stores of h into parity buffer
//   __syncthreads (vmcnt(0) drain => stores performed at coherence point)
//   tid==0: ONE relaxed fetch_add to the block's own 64B-padded counter
//   consumers: tid<128 poll the 128 counters with relaxed loads (s_sleep
//   paced) -> 8K spin loads/round device-wide (vs 262K in R2/R3)
//   data: 512 relaxed u64 loads/block, shared via LDS.
// Parity-2 ABA-safe: cnt[all]>=t+1 proves every block consumed h(t), so
// overwriting parity (t&1) with h(t+2) is safe (gate precedes store).
// ---------------------------------------------------------------------------
__global__ __launch_bounds__(512, 1) void k_rnn(
    const int* __restrict__ diag, const int* __restrict__ proc,
    const int* __restrict__ med,  const int* __restrict__ dtok,
    const float* __restrict__ enc, const float* __restrict__ dec,
    const float* __restrict__ attw,
    const float* __restrict__ wih, const float* __restrict__ whh,
    const float* __restrict__ bih, const float* __restrict__ bhh,
    float* __restrict__ ctx_ws, float* __restrict__ c_ws,
    unsigned* __restrict__ cnt, float* __restrict__ hbuf,
    float* __restrict__ hrelu)
{
    const int b = blockIdx.x, tid = threadIdx.x;
    const int w = tid >> 6, l = tid & 63;

    __shared__ float Wx[24 * 1024];     // 96KB: W_ih x-half, row (g*8+w)
    __shared__ float sm[320];
    __shared__ float red1[8], red2[8];
    __shared__ float hlds[1024];

    // ---- Phase A: clear own counter + ctx scores ----
    if (tid == 0)
        __hip_atomic_store(&cnt[b * 16], 0u, __ATOMIC_RELAXED, __HIP_MEMORY_SCOPE_AGENT);
    if (b < 40) {
        int i = 8*b + w;   // 0..319
        int ridx = (i < 128) ? diag[i] : (i < 192 ? proc[i-128] : med[i-192]);
        const float4* row = (const float4*)(enc + (size_t)ridx * EDIM);
        const float4* we  = (const float4*)(attw + EDIM);   // w_e = attn_w[0,E:]
        float p = 0.f;
        #pragma unroll
        for (int m = 0; m < 4; m++) p += dot4(row[l + 64*m], we[l + 64*m]);
        #pragma unroll
        for (int off = 32; off; off >>= 1) p += __shfl_xor(p, off);
        if (l == 0) ctx_ws[i] = p;
    }
    __threadfence();
    cooperative_groups::this_grid().sync();
    __threadfence();

    // ---- Phase B: per-block softmax (redundant) + c slice ----
    {
        float s1 = (tid < 320) ? ctx_ws[tid] : -1e30f;
        float mx = s1;
        #pragma unroll
        for (int off = 32; off; off >>= 1) mx = fmaxf(mx, __shfl_xor(mx, off));
        if (l == 0) red1[w] = mx;
        __syncthreads();
        mx = red1[0];
        #pragma unroll
        for (int k = 1; k < 8; k++) mx = fmaxf(mx, red1[k]);
        float e1 = (tid < 320) ? expf(s1 - mx) : 0.f;
        float ss = e1;
        #pragma unroll
        for (int off = 32; off; off >>= 1) ss += __shfl_xor(ss, off);
        if (l == 0) red2[w] = ss;
        __syncthreads();
        float tot = red2[0];
        #pragma unroll
        for (int k = 1; k < 8; k++) tot += red2[k];
        if (tid < 320) sm[tid] = e1 / tot;
        __syncthreads();

        int e = 8*b + w;   // c element this wave produces
        float p = 0.f;
        for (int i = l; i < 320; i += 64) {
            int ridx = (i < 128) ? diag[i] : (i < 192 ? proc[i-128] : med[i-192]);
            p += sm[i] * enc[(size_t)ridx * EDIM + e];
        }
        #pragma unroll
        for (int off = 32; off; off >>= 1) p += __shfl_xor(p, off);
        if (l == 0) c_ws[e] = p;
    }
    __threadfence();
    cooperative_groups::this_grid().sync();
    __threadfence();

    // ---- Phase C ----
    const int jr = 8*b + w, jz = 1024 + jr, jn = 2048 + jr;

    // W_ih x-half rows -> LDS
    {
        const float4* s_r = (const float4*)(wih + (size_t)jr * 2048 + 1024);
        const float4* s_z = (const float4*)(wih + (size_t)jz * 2048 + 1024);
        const float4* s_n = (const float4*)(wih + (size_t)jn * 2048 + 1024);
        float4* d_r = (float4*)(Wx + (0*8 + w) * 1024);
        float4* d_z = (float4*)(Wx + (1*8 + w) * 1024);
        float4* d_n = (float4*)(Wx + (2*8 + w) * 1024);
        #pragma unroll
        for (int m = 0; m < 4; m++) {
            d_r[l + 64*m] = s_r[l + 64*m];
            d_z[l + 64*m] = s_z[l + 64*m];
            d_n[l + 64*m] = s_n[l + 64*m];
        }
    }

    // W_hh rows -> VGPRs
    float4 whr[4], whz[4], whn[4];
    {
        const float4* qr = (const float4*)(whh + (size_t)jr * 1024);
        const float4* qz = (const float4*)(whh + (size_t)jz * 1024);
        const float4* qn = (const float4*)(whh + (size_t)jn * 1024);
        #pragma unroll
        for (int m = 0; m < 4; m++) { whr[m] = qr[l + 64*m]; whz[m] = qz[l + 64*m]; whn[m] = qn[l + 64*m]; }
    }

    float4 c4[4], h4[4];
    {
        const float4* cp = (const float4*)c_ws;
        const float4* hp = (const float4*)(dec + (size_t)V0TOK * EDIM);  // h0 = x_0
        #pragma unroll
        for (int m = 0; m < 4; m++) { c4[m] = cp[l + 64*m]; h4[m] = hp[l + 64*m]; }
    }
    const float b_r  = bih[jr] + bhh[jr];
    const float b_z  = bih[jz] + bhh[jz];
    const float b_ni = bih[jn];
    const float b_nh = bhh[jn];

    float gic_r = 0.f, gic_z = 0.f, gic_n = 0.f;
    {
        const float4* pr = (const float4*)(wih + (size_t)jr * 2048);
        const float4* pz = (const float4*)(wih + (size_t)jz * 2048);
        const float4* pn = (const float4*)(wih + (size_t)jn * 2048);
        #pragma unroll
        for (int m = 0; m < 4; m++) {
            gic_r += dot4(pr[l + 64*m], c4[m]);
            gic_z += dot4(pz[l + 64*m], c4[m]);
            gic_n += dot4(pn[l + 64*m], c4[m]);
        }
    }

    __syncthreads();   // Wx staged

    const float4* WxR = (const float4*)(Wx + (0*8 + w) * 1024);
    const float4* WxZ = (const float4*)(Wx + (1*8 + w) * 1024);
    const float4* WxN = (const float4*)(Wx + (2*8 + w) * 1024);

    int tokreg = dtok[l];

    // gx for t=0 (x_0 == h0)
    float gxr = gic_r, gxz = gic_z, gxn = gic_n;
    #pragma unroll
    for (int m = 0; m < 4; m++) {
        gxr += dot4(WxR[l + 64*m], h4[m]);
        gxz += dot4(WxZ[l + 64*m], h4[m]);
        gxn += dot4(WxN[l + 64*m], h4[m]);
    }
    float4 xv[4];
    {
        int tok1 = __shfl(tokreg, 0);
        const float4* xp = (const float4*)(dec + (size_t)tok1 * EDIM);
        #pragma unroll
        for (int m = 0; m < 4; m++) xv[m] = xp[l + 64*m];
    }

    // h[j] extraction constants (wave-uniform): j = 4*li + 256*mi + ci
    const int jmi = jr >> 8, jli = (jr & 255) >> 2, jci = jr & 3;

    for (int t = 0; t < 65; t++) {
        float hr = 0.f, hz = 0.f, hn_ = 0.f;
        #pragma unroll
        for (int m = 0; m < 4; m++) {
            hr  += dot4(whr[m], h4[m]);
            hz  += dot4(whz[m], h4[m]);
            hn_ += dot4(whn[m], h4[m]);
        }
        float sr = gxr + hr, sz = gxz + hz, sni = gxn, snh = hn_;
        #pragma unroll
        for (int off = 32; off; off >>= 1) {
            sr  += __shfl_xor(sr, off);  sz  += __shfl_xor(sz, off);
            sni += __shfl_xor(sni, off); snh += __shfl_xor(snh, off);
        }
        float rg = 1.f / (1.f + expf(-(sr + b_r)));
        float zg = 1.f / (1.f + expf(-(sz + b_z)));
        float ng = tanhf(sni + b_ni + rg * (snh + b_nh));

        float4 hs = (jmi == 0) ? h4[0] : (jmi == 1) ? h4[1] : (jmi == 2) ? h4[2] : h4[3];
        float hv0 = (jci == 0) ? hs.x : (jci == 1) ? hs.y : (jci == 2) ? hs.z : hs.w;
        float hv = __shfl(hv0, jli);
        float hnew = (1.f - zg) * ng + zg * hv;

        if (t < 64) {
            const int par = (t + 1) & 1;
            if (l == 0) {
                hrelu[t * 1024 + jr] = fmaxf(hnew, 0.f);
                __hip_atomic_store(&hbuf[par * 1024 + jr], hnew,
                                   __ATOMIC_RELAXED, __HIP_MEMORY_SCOPE_AGENT);
            }
            __syncthreads();        // drains all 8 waves' stores (vmcnt 0)
            if (tid == 0)
                __hip_atomic_fetch_add(&cnt[b * 16], 1u,
                                       __ATOMIC_RELAXED, __HIP_MEMORY_SCOPE_AGENT);

            // ---- overlap window: gx(t+1) + x prefetch while adds land ----
            gxr = gic_r; gxz = gic_z; gxn = gic_n;
            #pragma unroll
            for (int m = 0; m < 4; m++) {
                gxr += dot4(WxR[l + 64*m], xv[m]);
                gxz += dot4(WxZ[l + 64*m], xv[m]);
                gxn += dot4(WxN[l + 64*m], xv[m]);
            }
            if (t < 63) {
                int tok = __shfl(tokreg, t + 1);
                const float4* xp = (const float4*)(dec + (size_t)tok * EDIM);
                #pragma unroll
                for (int m = 0; m < 4; m++) xv[m] = xp[l + 64*m];
            }

            // ---- poll 128 padded counters, relaxed only ----
            if (tid < 128) {
                const unsigned target = (unsigned)(t + 1);
                while (__hip_atomic_load(&cnt[tid * 16], __ATOMIC_RELAXED,
                                         __HIP_MEMORY_SCOPE_AGENT) < target)
                    __builtin_amdgcn_s_sleep(1);
            }
            __syncthreads();

            // ---- fetch h(t+1): one u64 per thread, share via LDS ----
            u64 v = __hip_atomic_load((u64*)hbuf + par * 512 + tid,
                                      __ATOMIC_RELAXED, __HIP_MEMORY_SCOPE_AGENT);
            ((u64*)hlds)[tid] = v;
            __syncthreads();
            #pragma unroll
            for (int m = 0; m < 4; m++) h4[m] = ((const float4*)hlds)[l + 64*m];
        } else {
            if (l == 0) hrelu[64 * 1024 + jr] = fmaxf(hnew, 0.f);
        }
    }
}

// ---------------------------------------------------------------------------
// logits = out_w @ relu(H)^T + out_b.
// Block 512 thr, tile 32 v x 65 t. Thread (q=tid&15, s=(tid>>4)&7, g=tid>>7):
// 8 v-rows (v0+8g+r), t = s+8*ti (ti<9, t<65), k-slice 4q of each 64-chunk.
// One 16B LDS read feeds 32 FMAs (0.5 B/FMA); W float4 kept in regs; acc[8][9]
// fully static. Reduce over q (16-lane shfl), stage output in LDS, store
// coalesced.
// ---------------------------------------------------------------------------
__global__ __launch_bounds__(512) void k_logits(
    const float* __restrict__ wo, const float* __restrict__ bo,
    const float* __restrict__ hrelu, float* __restrict__ out)
{
    __shared__ float Hs[65 * 68];     // 17.7KB; reused as Os[65][33] at the end
    const int tid = threadIdx.x;
    const int q = tid & 15, s = (tid >> 4) & 7, g = tid >> 7;
    const int v0 = blockIdx.x * 32;
    const int vb = v0 + 8 * g;        // this thread's first row

    const float* wbase = wo + (size_t)((vb < 32002) ? vb : 0) * 1024;

    float acc[8][9];
    #pragma unroll
    for (int r = 0; r < 8; r++)
        #pragma unroll
        for (int ti = 0; ti < 9; ti++) acc[r][ti] = 0.f;

    for (int kc = 0; kc < 16; kc++) {
        __syncthreads();
        for (int idx = tid; idx < 65 * 16; idx += 512) {
            int t = idx >> 4, m = idx & 15;
            *(float4*)(Hs + t * 68 + 4 * m) =
                *(const float4*)(hrelu + t * 1024 + kc * 64 + 4 * m);
        }
        float4 wv[8];
        #pragma unroll
        for (int r = 0; r < 8; r++) {
            int v = vb + r;
            const float* wr = (v < 32002) ? (wbase + (size_t)r * 1024) : wbase;
            wv[r] = *(const float4*)(wr + kc * 64 + 4 * q);
        }
        __syncthreads();

        #pragma unroll
        for (int ti = 0; ti < 9; ti++) {
            int t = s + 8 * ti;
            if (t < 65) {
                float4 h4 = *(const float4*)(Hs + t * 68 + 4 * q);
                #pragma unroll
                for (int r = 0; r < 8; r++) {
                    acc[r][ti] = fmaf(wv[r].x, h4.x, acc[r][ti]);
                    acc[r][ti] = fmaf(wv[r].y, h4.y, acc[r][ti]);
                    acc[r][ti] = fmaf(wv[r].z, h4.z, acc[r][ti]);
                    acc[r][ti] = fmaf(wv[r].w, h4.w, acc[r][ti]);
                }
            }
        }
    }

    // reduce over q (16-lane groups), stage into LDS (reuse Hs as Os[65][33])
    __syncthreads();
    float* Os = Hs;
    #pragma unroll
    for (int ti = 0; ti < 9; ti++) {
        int t = s + 8 * ti;
        #pragma unroll
        for (int r = 0; r < 8; r++) {
            float sum = acc[r][ti];
            sum += __shfl_xor(sum, 1);
            sum += __shfl_xor(sum, 2);
            sum += __shfl_xor(sum, 4);
            sum += __shfl_xor(sum, 8);
            if (q == 0 && t < 65) Os[t * 33 + 8 * g + r] = sum;
        }
    }
    __syncthreads();
    for (int idx = tid; idx < 65 * 32; idx += 512) {
        int t = idx >> 5, c = idx & 31;
        int v = v0 + c;
        if (v < 32002) out[(size_t)t * 32002 + v] = Os[t * 33 + c] + bo[v];
    }
}

// ---------------------------------------------------------------------------
extern "C" void kernel_launch(void* const* d_in, const int* in_sizes, int n_in,
                              void* d_out, int out_size, void* d_ws, size_t ws_size,
                              hipStream_t stream) {
    const int*   diag = (const int*)d_in[0];
    const int*   proc = (const int*)d_in[1];
    const int*   med  = (const int*)d_in[2];
    const int*   dtok = (const int*)d_in[3];
    const float* enc  = (const float*)d_in[4];
    const float* dec  = (const float*)d_in[5];
    const float* attw = (const float*)d_in[6];
    // d_in[7] = attn_b: uniform shift, cancels in softmax -> unused
    const float* wih  = (const float*)d_in[8];
    const float* whh  = (const float*)d_in[9];
    const float* bih  = (const float*)d_in[10];
    const float* bhh  = (const float*)d_in[11];
    const float* wo   = (const float*)d_in[12];
    const float* bo   = (const float*)d_in[13];
    float* out = (float*)d_out;

    // ws: [0,1280) ctx | [2048,6144) c | [8192,+8192) cnt(128x64B) |
    //     [16384,+8192) hbuf | [32768,+266240) hrelu
    float*    ctx_ws = (float*)d_ws;
    float*    c_ws   = (float*)((char*)d_ws + 2048);
    unsigned* cnt    = (unsigned*)((char*)d_ws + 8192);
    float*    hbuf   = (float*)((char*)d_ws + 16384);
    float*    hrelu  = (float*)((char*)d_ws + 32768);

    void* args[] = { (void*)&diag, (void*)&proc, (void*)&med, (void*)&dtok,
                     (void*)&enc, (void*)&dec, (void*)&attw,
                     (void*)&wih, (void*)&whh, (void*)&bih, (void*)&bhh,
                     (void*)&ctx_ws, (void*)&c_ws, (void*)&cnt, (void*)&hbuf,
                     (void*)&hrelu };
    hipLaunchCooperativeKernel((void*)k_rnn, dim3(128), dim3(512), args, 0, stream);

    k_logits<<<dim3(1001), dim3(512), 0, stream>>>(wo, bo, hrelu, out);
}

// Round 6
// 461.537 us; speedup vs baseline: 4.8350x; 1.1108x over previous
//
#include <hip/hip_runtime.h>
#include <hip/hip_cooperative_groups.h>

typedef unsigned long long u64;
#define V0TOK 32000
#define EDIM  1024

__device__ __forceinline__ float dot4(float4 a, float4 b) {
    return fmaf(a.x, b.x, fmaf(a.y, b.y, fmaf(a.z, b.z, a.w * b.w)));
}

// ---------------------------------------------------------------------------
// Cooperative RNN: 128 blocks x 512 threads (8 waves). Block b owns h rows
// j = 8b+w (wave w): GRU rows {j, 1024+j, 2048+j}. W_hh in VGPRs, W_ih x-half
// in LDS (96KB), c-half folded into gic once.
// h exchange: single packed {tag,value} u64 relaxed agent store per value
// (fire-and-forget: no vmcnt drain, no counter, no ordering op -- R4 showed
// agent REL/ACQ = L2 flush storm; R5 showed store-ack + add + separate data
// fetch = 3 serial fabric RTs). Consumer: each thread polls ITS OWN 2 slots
// until tag==t+1; the successful poll already holds the data -> LDS share.
// Parity double buffer; distance-2 backpressure makes tag aliasing
// impossible (block writing h(t+3) over parity p implies every block read
// h(t+1) from p). hbuf tags cleared each launch (replay determinism).
// ---------------------------------------------------------------------------
__global__ __launch_bounds__(512, 1) void k_rnn(
    const int* __restrict__ diag, const int* __restrict__ proc,
    const int* __restrict__ med,  const int* __restrict__ dtok,
    const float* __restrict__ enc, const float* __restrict__ dec,
    const float* __restrict__ attw,
    const float* __restrict__ wih, const float* __restrict__ whh,
    const float* __restrict__ bih, const float* __restrict__ bhh,
    float* __restrict__ ctx_ws, float* __restrict__ c_ws,
    u64* __restrict__ hbuf, float* __restrict__ hrelu)
{
    const int b = blockIdx.x, tid = threadIdx.x;
    const int w = tid >> 6, l = tid & 63;

    __shared__ float Wx[24 * 1024];     // 96KB: W_ih x-half, row (g*8+w)
    __shared__ float sm[320];
    __shared__ float red1[8], red2[8];
    __shared__ float hlds[1024];

    // ---- Phase A: clear hbuf tags (blocks 0-3) + ctx scores (blocks <40) ----
    if (b < 4)
        __hip_atomic_store(&hbuf[b * 512 + tid], 0ull,
                           __ATOMIC_RELAXED, __HIP_MEMORY_SCOPE_AGENT);
    if (b < 40) {
        int i = 8*b + w;   // 0..319
        int ridx = (i < 128) ? diag[i] : (i < 192 ? proc[i-128] : med[i-192]);
        const float4* row = (const float4*)(enc + (size_t)ridx * EDIM);
        const float4* we  = (const float4*)(attw + EDIM);   // w_e = attn_w[0,E:]
        float p = 0.f;
        #pragma unroll
        for (int m = 0; m < 4; m++) p += dot4(row[l + 64*m], we[l + 64*m]);
        #pragma unroll
        for (int off = 32; off; off >>= 1) p += __shfl_xor(p, off);
        if (l == 0) ctx_ws[i] = p;
    }
    __threadfence();
    cooperative_groups::this_grid().sync();
    __threadfence();

    // ---- Phase B: per-block softmax (redundant) + c slice ----
    {
        float s1 = (tid < 320) ? ctx_ws[tid] : -1e30f;
        float mx = s1;
        #pragma unroll
        for (int off = 32; off; off >>= 1) mx = fmaxf(mx, __shfl_xor(mx, off));
        if (l == 0) red1[w] = mx;
        __syncthreads();
        mx = red1[0];
        #pragma unroll
        for (int k = 1; k < 8; k++) mx = fmaxf(mx, red1[k]);
        float e1 = (tid < 320) ? expf(s1 - mx) : 0.f;
        float ss = e1;
        #pragma unroll
        for (int off = 32; off; off >>= 1) ss += __shfl_xor(ss, off);
        if (l == 0) red2[w] = ss;
        __syncthreads();
        float tot = red2[0];
        #pragma unroll
        for (int k = 1; k < 8; k++) tot += red2[k];
        if (tid < 320) sm[tid] = e1 / tot;
        __syncthreads();

        int e = 8*b + w;
        float p = 0.f;
        for (int i = l; i < 320; i += 64) {
            int ridx = (i < 128) ? diag[i] : (i < 192 ? proc[i-128] : med[i-192]);
            p += sm[i] * enc[(size_t)ridx * EDIM + e];
        }
        #pragma unroll
        for (int off = 32; off; off >>= 1) p += __shfl_xor(p, off);
        if (l == 0) c_ws[e] = p;
    }
    __threadfence();
    cooperative_groups::this_grid().sync();
    __threadfence();

    // ---- Phase C ----
    const int jr = 8*b + w, jz = 1024 + jr, jn = 2048 + jr;

    // W_ih x-half rows -> LDS
    {
        const float4* s_r = (const float4*)(wih + (size_t)jr * 2048 + 1024);
        const float4* s_z = (const float4*)(wih + (size_t)jz * 2048 + 1024);
        const float4* s_n = (const float4*)(wih + (size_t)jn * 2048 + 1024);
        float4* d_r = (float4*)(Wx + (0*8 + w) * 1024);
        float4* d_z = (float4*)(Wx + (1*8 + w) * 1024);
        float4* d_n = (float4*)(Wx + (2*8 + w) * 1024);
        #pragma unroll
        for (int m = 0; m < 4; m++) {
            d_r[l + 64*m] = s_r[l + 64*m];
            d_z[l + 64*m] = s_z[l + 64*m];
            d_n[l + 64*m] = s_n[l + 64*m];
        }
    }

    // W_hh rows -> VGPRs
    float4 whr[4], whz[4], whn[4];
    {
        const float4* qr = (const float4*)(whh + (size_t)jr * 1024);
        const float4* qz = (const float4*)(whh + (size_t)jz * 1024);
        const float4* qn = (const float4*)(whh + (size_t)jn * 1024);
        #pragma unroll
        for (int m = 0; m < 4; m++) { whr[m] = qr[l + 64*m]; whz[m] = qz[l + 64*m]; whn[m] = qn[l + 64*m]; }
    }

    float4 c4[4], h4[4];
    {
        const float4* cp = (const float4*)c_ws;
        const float4* hp = (const float4*)(dec + (size_t)V0TOK * EDIM);  // h0 = x_0
        #pragma unroll
        for (int m = 0; m < 4; m++) { c4[m] = cp[l + 64*m]; h4[m] = hp[l + 64*m]; }
    }
    const float b_r  = bih[jr] + bhh[jr];
    const float b_z  = bih[jz] + bhh[jz];
    const float b_ni = bih[jn];
    const float b_nh = bhh[jn];

    float gic_r = 0.f, gic_z = 0.f, gic_n = 0.f;
    {
        const float4* pr = (const float4*)(wih + (size_t)jr * 2048);
        const float4* pz = (const float4*)(wih + (size_t)jz * 2048);
        const float4* pn = (const float4*)(wih + (size_t)jn * 2048);
        #pragma unroll
        for (int m = 0; m < 4; m++) {
            gic_r += dot4(pr[l + 64*m], c4[m]);
            gic_z += dot4(pz[l + 64*m], c4[m]);
            gic_n += dot4(pn[l + 64*m], c4[m]);
        }
    }

    __syncthreads();   // Wx staged

    const float4* WxR = (const float4*)(Wx + (0*8 + w) * 1024);
    const float4* WxZ = (const float4*)(Wx + (1*8 + w) * 1024);
    const float4* WxN = (const float4*)(Wx + (2*8 + w) * 1024);

    int tokreg = dtok[l];

    // gx for t=0 (x_0 == h0)
    float gxr = gic_r, gxz = gic_z, gxn = gic_n;
    #pragma unroll
    for (int m = 0; m < 4; m++) {
        gxr += dot4(WxR[l + 64*m], h4[m]);
        gxz += dot4(WxZ[l + 64*m], h4[m]);
        gxn += dot4(WxN[l + 64*m], h4[m]);
    }
    float4 xv[4];
    {
        int tok1 = __shfl(tokreg, 0);
        const float4* xp = (const float4*)(dec + (size_t)tok1 * EDIM);
        #pragma unroll
        for (int m = 0; m < 4; m++) xv[m] = xp[l + 64*m];
    }

    // h[j] extraction constants (wave-uniform)
    const int jmi = jr >> 8, jli = (jr >> 2) & 63, jci = jr & 3;

    for (int t = 0; t < 65; t++) {
        float hr = 0.f, hz = 0.f, hn_ = 0.f;
        #pragma unroll
        for (int m = 0; m < 4; m++) {
            hr  += dot4(whr[m], h4[m]);
            hz  += dot4(whz[m], h4[m]);
            hn_ += dot4(whn[m], h4[m]);
        }
        float sr = gxr + hr, sz = gxz + hz, sni = gxn, snh = hn_;
        #pragma unroll
        for (int off = 32; off; off >>= 1) {
            sr  += __shfl_xor(sr, off);  sz  += __shfl_xor(sz, off);
            sni += __shfl_xor(sni, off); snh += __shfl_xor(snh, off);
        }
        float rg = 1.f / (1.f + expf(-(sr + b_r)));
        float zg = 1.f / (1.f + expf(-(sz + b_z)));
        float ng = tanhf(sni + b_ni + rg * (snh + b_nh));

        float4 hs = (jmi == 0) ? h4[0] : (jmi == 1) ? h4[1] : (jmi == 2) ? h4[2] : h4[3];
        float hv0 = (jci == 0) ? hs.x : (jci == 1) ? hs.y : (jci == 2) ? hs.z : hs.w;
        float hv = __shfl(hv0, jli);
        float hnew = (1.f - zg) * ng + zg * hv;

        if (t < 64) {
            const int par = (t + 1) & 1;
            const unsigned tag = (unsigned)(t + 1);
            if (l == 0) {
                hrelu[t * 1024 + jr] = fmaxf(hnew, 0.f);
                u64 pk = ((u64)tag << 32) | (u64)__float_as_uint(hnew);
                __hip_atomic_store(&hbuf[par * 1024 + jr], pk,
                                   __ATOMIC_RELAXED, __HIP_MEMORY_SCOPE_AGENT);
            }

            // ---- overlap: gx(t+1) + x prefetch while stores fly ----
            gxr = gic_r; gxz = gic_z; gxn = gic_n;
            #pragma unroll
            for (int m = 0; m < 4; m++) {
                gxr += dot4(WxR[l + 64*m], xv[m]);
                gxz += dot4(WxZ[l + 64*m], xv[m]);
                gxn += dot4(WxN[l + 64*m], xv[m]);
            }
            if (t < 63) {
                int tok = __shfl(tokreg, t + 1);
                const float4* xp = (const float4*)(dec + (size_t)tok * EDIM);
                #pragma unroll
                for (int m = 0; m < 4; m++) xv[m] = xp[l + 64*m];
            }

            // ---- poll own 2 slots; poll result IS the data ----
            {
                u64* hb = hbuf + par * 1024;
                u64 va, vb2;
                while (1) {
                    va  = __hip_atomic_load(&hb[2*tid],     __ATOMIC_RELAXED, __HIP_MEMORY_SCOPE_AGENT);
                    vb2 = __hip_atomic_load(&hb[2*tid + 1], __ATOMIC_RELAXED, __HIP_MEMORY_SCOPE_AGENT);
                    if (((unsigned)(va >> 32) == tag) & ((unsigned)(vb2 >> 32) == tag)) break;
                }
                hlds[2*tid]     = __uint_as_float((unsigned)va);
                hlds[2*tid + 1] = __uint_as_float((unsigned)vb2);
            }
            __syncthreads();
            #pragma unroll
            for (int m = 0; m < 4; m++) h4[m] = ((const float4*)hlds)[l + 64*m];
            __syncthreads();
        } else {
            if (l == 0) hrelu[64 * 1024 + jr] = fmaxf(hnew, 0.f);
        }
    }
}

// ---------------------------------------------------------------------------
// logits = out_w @ relu(H)^T + out_b, owner-computes:
// block = 16 v-rows, 256 thr; thread (vl=tid>>4, q=tid&15) owns W[v] k-slice
// 4q of each 64-chunk (256B coalesced per 16 lanes), acc[65] static in VGPRs.
// Latency engineering: stage loads for kc+1 issued before compute of kc
// (T14 split), W double-buffered in regs; __launch_bounds__(256,4) keeps
// VGPR<=128 -> 4 blocks/CU. Epilogue: 16-lane shfl reduce, LDS stage,
// coalesced store.
// ---------------------------------------------------------------------------
__global__ __launch_bounds__(256, 4) void k_logits(
    const float* __restrict__ wo, const float* __restrict__ bo,
    const float* __restrict__ hrelu, float* __restrict__ out)
{
    __shared__ float Hs[65 * 68];     // 17.7KB; reused as Os[65][17] at the end
    const int tid = threadIdx.x, q = tid & 15, vl = tid >> 4;
    const int v0 = blockIdx.x * 16;
    const int v  = v0 + vl;
    const int vc = (v < 32002) ? v : 32001;
    const float* wrow = wo + (size_t)vc * 1024;

    float acc[65];
    #pragma unroll
    for (int t = 0; t < 65; t++) acc[t] = 0.f;

    // stage registers: 4 float4/thread + 1 extra for tid<16 (65*16 = 1040)
    float4 st0, st1, st2, st3, st4;
    #define ISSUE(kc_) do {                                                   \
        int base = (kc_) * 64;                                                \
        { int idx = tid;       st0 = *(const float4*)(hrelu + (idx>>4)*1024 + base + 4*(idx&15)); } \
        { int idx = tid + 256; st1 = *(const float4*)(hrelu + (idx>>4)*1024 + base + 4*(idx&15)); } \
        { int idx = tid + 512; st2 = *(const float4*)(hrelu + (idx>>4)*1024 + base + 4*(idx&15)); } \
        { int idx = tid + 768; st3 = *(const float4*)(hrelu + (idx>>4)*1024 + base + 4*(idx&15)); } \
        if (tid < 16) st4 = *(const float4*)(hrelu + 64*1024 + base + 4*tid); \
    } while (0)
    #define WRITE() do {                                                      \
        { int idx = tid;       *(float4*)(Hs + (idx>>4)*68 + 4*(idx&15)) = st0; } \
        { int idx = tid + 256; *(float4*)(Hs + (idx>>4)*68 + 4*(idx&15)) = st1; } \
        { int idx = tid + 512; *(float4*)(Hs + (idx>>4)*68 + 4*(idx&15)) = st2; } \
        { int idx = tid + 768; *(float4*)(Hs + (idx>>4)*68 + 4*(idx&15)) = st3; } \
        if (tid < 16) *(float4*)(Hs + 64*68 + 4*tid) = st4;                   \
    } while (0)

    ISSUE(0);
    float4 wv = *(const float4*)(wrow + 4*q);

    for (int kc = 0; kc < 16; kc++) {
        WRITE();                       // consumes stage regs of kc
        __syncthreads();               // Hs(kc) ready
        float4 wnext;
        if (kc < 15) {
            ISSUE(kc + 1);             // in flight during compute
            wnext = *(const float4*)(wrow + (kc + 1) * 64 + 4*q);
        }
        const float* hp = Hs + 4*q;
        #pragma unroll
        for (int t = 0; t < 65; t++) {
            float4 h4 = *(const float4*)(hp + t * 68);
            acc[t] = fmaf(wv.x, h4.x, acc[t]);
            acc[t] = fmaf(wv.y, h4.y, acc[t]);
            acc[t] = fmaf(wv.z, h4.z, acc[t]);
            acc[t] = fmaf(wv.w, h4.w, acc[t]);
        }
        wv = wnext;
        __syncthreads();               // Hs consumed; next WRITE may proceed
    }

    // reduce over q (16-lane groups), stage Os[65][17], coalesced store
    float* Os = Hs;
    #pragma unroll
    for (int t = 0; t < 65; t++) {
        float s_ = acc[t];
        s_ += __shfl_xor(s_, 1);
        s_ += __shfl_xor(s_, 2);
        s_ += __shfl_xor(s_, 4);
        s_ += __shfl_xor(s_, 8);
        if (q == 0) Os[t * 17 + vl] = s_;
    }
    __syncthreads();
    for (int idx = tid; idx < 65 * 16; idx += 256) {
        int t = idx >> 4, c = idx & 15;
        int vv = v0 + c;
        if (vv < 32002) out[(size_t)t * 32002 + vv] = Os[t * 17 + c] + bo[vv];
    }
}

// ---------------------------------------------------------------------------
extern "C" void kernel_launch(void* const* d_in, const int* in_sizes, int n_in,
                              void* d_out, int out_size, void* d_ws, size_t ws_size,
                              hipStream_t stream) {
    const int*   diag = (const int*)d_in[0];
    const int*   proc = (const int*)d_in[1];
    const int*   med  = (const int*)d_in[2];
    const int*   dtok = (const int*)d_in[3];
    const float* enc  = (const float*)d_in[4];
    const float* dec  = (const float*)d_in[5];
    const float* attw = (const float*)d_in[6];
    // d_in[7] = attn_b: uniform shift, cancels in softmax -> unused
    const float* wih  = (const float*)d_in[8];
    const float* whh  = (const float*)d_in[9];
    const float* bih  = (const float*)d_in[10];
    const float* bhh  = (const float*)d_in[11];
    const float* wo   = (const float*)d_in[12];
    const float* bo   = (const float*)d_in[13];
    float* out = (float*)d_out;

    // ws: [0,1280) ctx | [2048,6144) c | [16384,+16384) hbuf(2x1024 u64) |
    //     [32768,+266240) hrelu
    float* ctx_ws = (float*)d_ws;
    float* c_ws   = (float*)((char*)d_ws + 2048);
    u64*   hbuf   = (u64*)  ((char*)d_ws + 16384);
    float* hrelu  = (float*)((char*)d_ws + 32768);

    void* args[] = { (void*)&diag, (void*)&proc, (void*)&med, (void*)&dtok,
                     (void*)&enc, (void*)&dec, (void*)&attw,
                     (void*)&wih, (void*)&whh, (void*)&bih, (void*)&bhh,
                     (void*)&ctx_ws, (void*)&c_ws, (void*)&hbuf, (void*)&hrelu };
    hipLaunchCooperativeKernel((void*)k_rnn, dim3(128), dim3(512), args, 0, stream);

    k_logits<<<dim3(2001), dim3(256), 0, stream>>>(wo, bo, hrelu, out);
}